// Round 4
// baseline (61.932 us; speedup 1.0000x reference)
//
#include <hip/hip_runtime.h>
#include <stdint.h>

#define EE 1024
#define SS 512
#define NBATCH 16
#define PP 96
#define NROWS (NBATCH * SS)   // 8192
#define NJ (PP * 4)           // 384
#define EPS 1e-8f

typedef __attribute__((ext_vector_type(8))) short bf16x8;
typedef __attribute__((ext_vector_type(4))) float f32x4;

// round-to-nearest-even f32 -> bf16 bits
__device__ __forceinline__ ushort f2bf(float f) {
    uint32_t u = __float_as_uint(f);
    u += 0x7fffu + ((u >> 16) & 1u);
    return (ushort)(u >> 16);
}

__device__ __forceinline__ void gload16(const void* g, void* l) {
    __builtin_amdgcn_global_load_lds(
        (const __attribute__((address_space(1))) uint32_t*)g,
        (__attribute__((address_space(3))) uint32_t*)l, 16, 0, 0);
}

// ---- fused convert: emb blocks (wave-per-row, 4 float4 per lane) + proto blocks ----
__global__ __launch_bounds__(256) void conv_kernel(const float* __restrict__ emb,
                                                   const float* __restrict__ proto,
                                                   ushort* __restrict__ ebf,
                                                   ushort* __restrict__ pbf,
                                                   float* __restrict__ rn2,
                                                   float* __restrict__ pn) {
    int b = blockIdx.x, t = threadIdx.x;
    if (b < NROWS / 4) {
        int r = b * 4 + (t >> 6);
        int l = t & 63;
        const float4* src = (const float4*)(emb + (size_t)r * EE);
        ushort4* dst = (ushort4*)(ebf + (size_t)r * EE);
        float s = 0.f;
#pragma unroll
        for (int i = 0; i < 4; i++) {
            float4 v = src[l + 64 * i];
            dst[l + 64 * i] = make_ushort4(f2bf(v.x), f2bf(v.y), f2bf(v.z), f2bf(v.w));
            s += v.x * v.x + v.y * v.y + v.z * v.z + v.w * v.w;
        }
#pragma unroll
        for (int off = 32; off; off >>= 1) s += __shfl_down(s, off);
        if (l == 0) rn2[r] = s;
    } else {
        int p = b - NROWS / 4;
        const float4* src = (const float4*)(proto + (size_t)p * 4096);
        ushort4* dst = (ushort4*)(pbf + (size_t)p * 4096);
        float s = 0.f;
#pragma unroll
        for (int i = 0; i < 4; i++) {
            float4 v = src[t + 256 * i];
            dst[t + 256 * i] = make_ushort4(f2bf(v.x), f2bf(v.y), f2bf(v.z), f2bf(v.w));
            s += v.x * v.x + v.y * v.y + v.z * v.z + v.w * v.w;
        }
#pragma unroll
        for (int off = 32; off; off >>= 1) s += __shfl_down(s, off);
        __shared__ float red[4];
        if ((t & 63) == 0) red[t >> 6] = s;
        __syncthreads();
        if (t == 0) pn[p] = sqrtf(red[0] + red[1] + red[2] + red[3]);
    }
}

// ---- bf16 MFMA GEMM: Rt[j][r] = sum_k A[r,k]*B[j,k]; 64x128 tile, K=1024 ----
#define GBM 64
#define GBN 128
#define GBK 64

__global__ __launch_bounds__(256) void gemm_kernel(const ushort* __restrict__ A,
                                                   const ushort* __restrict__ B,
                                                   float* __restrict__ Rt) {
    __shared__ ushort As[GBM * GBK];   // 8 KB
    __shared__ ushort Bs[GBN * GBK];   // 16 KB
    int bn = blockIdx.x >> 7;          // 0..2
    int bm = blockIdx.x & 127;         // 0..127
    int r0 = bm * GBM, j0 = bn * GBN;
    int tid = threadIdx.x;
    int lane = tid & 63;

    // staging: LDS chunk c (16B) at linear c*16; row=c>>3, cc=c&7.
    // LDS(row,cc) holds global chunk gc = cc ^ (row&7)  (involution)
    int srow = tid >> 3;
    int gc = (tid & 7) ^ (srow & 7);
    const ushort* ga = A + (size_t)(r0 + srow) * EE + gc * 8;
    const ushort* gb = B + (size_t)(j0 + srow) * EE + gc * 8;
    ushort* lA = As + tid * 8;
    ushort* lB = Bs + tid * 8;

    int w = tid >> 6;
    int wm = (w >> 1) * 32, wn = (w & 1) * 64;
    int kc = lane >> 4;       // k-chunk within 32-elem slice
    int fr = lane & 15;

    f32x4 acc[2][4] = {};

    for (int k0 = 0; k0 < EE; k0 += GBK) {
        __syncthreads();
        gload16(ga + k0, lA);
        gload16(ga + 32 * EE + k0, lA + 2048);
        gload16(gb + k0, lB);
        gload16(gb + 32 * EE + k0, lB + 2048);
        gload16(gb + 64 * EE + k0, lB + 4096);
        gload16(gb + 96 * EE + k0, lB + 6144);
        __syncthreads();
        bf16x8 af[2][2], bf[4][2];
#pragma unroll
        for (int m = 0; m < 2; m++) {
            int row = wm + m * 16 + fr;
#pragma unroll
            for (int kk = 0; kk < 2; kk++) {
                int cc = (kk * 4 + kc) ^ (row & 7);
                af[m][kk] = *(const bf16x8*)(As + row * GBK + cc * 8);
            }
        }
#pragma unroll
        for (int n = 0; n < 4; n++) {
            int row = wn + n * 16 + fr;
#pragma unroll
            for (int kk = 0; kk < 2; kk++) {
                int cc = (kk * 4 + kc) ^ (row & 7);
                bf[n][kk] = *(const bf16x8*)(Bs + row * GBK + cc * 8);
            }
        }
#pragma unroll
        for (int m = 0; m < 2; m++)
#pragma unroll
            for (int n = 0; n < 4; n++)
#pragma unroll
                for (int kk = 0; kk < 2; kk++)
                    acc[m][n] = __builtin_amdgcn_mfma_f32_16x16x32_bf16(af[m][kk], bf[n][kk], acc[m][n], 0, 0, 0);
    }

    int rloc = r0 + wm + (lane >> 4) * 4;
    int jloc = j0 + wn + fr;
#pragma unroll
    for (int m = 0; m < 2; m++)
#pragma unroll
        for (int n = 0; n < 4; n++)
            *(f32x4*)(Rt + (size_t)(jloc + n * 16) * NROWS + rloc + m * 16) = acc[m][n];
}

// ---- combine: min-pool of -cos over window positions; fused FC via atomics ----
__global__ __launch_bounds__(256) void combine_kernel(const float* __restrict__ Rt,
                                                      const float* __restrict__ rn2,
                                                      const float* __restrict__ pn,
                                                      const float* __restrict__ fcw,
                                                      float* __restrict__ out,
                                                      float* __restrict__ cls) {
    int wave = threadIdx.x >> 6;
    int lane = threadIdx.x & 63;
    int pair = blockIdx.x * 4 + wave;   // 1536
    int n = pair / PP;
    int p = pair % PP;
    int d = (p >> 5) + 1;
    int H = SS - 3 * d;
    float pnv = fmaxf(pn[p], EPS);
    float best = -3.4e38f;
    for (int h = lane; h < H; h += 64) {
        float dot = 0.f, x2 = 0.f;
#pragma unroll
        for (int j = 0; j < 4; j++) {
            int q = h * 4 + j;
            int k = q / H;
            int s = q - k * H + k * d;
            int r = n * SS + s;
            dot += Rt[(size_t)(4 * p + j) * NROWS + r];
            x2 += rn2[r];
        }
        float xn = fmaxf(sqrtf(x2), EPS);
        best = fmaxf(best, dot / (xn * pnv));
    }
#pragma unroll
    for (int off = 32; off; off >>= 1) best = fmaxf(best, __shfl_down(best, off));
    if (lane == 0) {
        float pdv = -best;
        out[n * PP + p] = pdv;
        atomicAdd(&cls[n * 2 + 0], pdv * fcw[p]);
        atomicAdd(&cls[n * 2 + 1], pdv * fcw[PP + p]);
    }
}

extern "C" void kernel_launch(void* const* d_in, const int* in_sizes, int n_in,
                              void* d_out, int out_size, void* d_ws, size_t ws_size,
                              hipStream_t stream) {
    const float* emb = (const float*)d_in[0];     // (16,512,1024) f32
    const float* proto = (const float*)d_in[2];   // (96,1024,4) f32 flat = (384,1024)
    const float* fcw = (const float*)d_in[3];     // (2,96)
    float* out = (float*)d_out;
    float* cls = out + NBATCH * PP;

    uint8_t* ws = (uint8_t*)d_ws;
    ushort* ebf = (ushort*)ws;                                   // 16 MB
    ushort* pbf = (ushort*)(ws + (size_t)NROWS * EE * 2);        // 0.75 MB
    float* rn2 = (float*)(ws + (size_t)NROWS * EE * 2 + (size_t)NJ * EE * 2);
    float* pn = rn2 + NROWS;
    float* Rt = pn + 128;  // 16B-aligned

    hipMemsetAsync(cls, 0, NBATCH * 2 * sizeof(float), stream);
    conv_kernel<<<NROWS / 4 + PP, 256, 0, stream>>>(emb, proto, ebf, pbf, rn2, pn);
    gemm_kernel<<<3 * 128, 256, 0, stream>>>(ebf, pbf, Rt);
    combine_kernel<<<NBATCH * PP / 4, 256, 0, stream>>>(Rt, rn2, pn, fcw, out, cls);
}